// Round 2
// baseline (8435.243 us; speedup 1.0000x reference)
//
#include <hip/hip_runtime.h>
#include <math.h>

#define NN 32768       // nodes
#define NE 524288      // edges
#define NB 256         // graphs/batch
#define HID 64
#define NL 3
#define EPS_AGG 1e-6f
#define EPS_BN 1e-5f

typedef _Float16 h16;

// ---------------- utility: zero a float buffer (float4 granularity) ----------------

__global__ void k_zero4(float4* __restrict__ p, long n4) {
    long t = (long)blockIdx.x * blockDim.x + threadIdx.x;
    long stride = (long)gridDim.x * blockDim.x;
    float4 z = {0.f, 0.f, 0.f, 0.f};
    for (; t < n4; t += stride) p[t] = z;
}

// ---------------- embedding kernels ----------------

__global__ void k_embed_h(const float* __restrict__ hin, const float* __restrict__ W,
                          const float* __restrict__ b, float* __restrict__ out) {
    int tid = blockIdx.x * blockDim.x + threadIdx.x;   // NN*64 threads
    int i = tid >> 6, j = tid & 63;
    float acc = b[j];
#pragma unroll
    for (int k = 0; k < 6; ++k) acc += hin[i * 6 + k] * W[k * 64 + j];
    out[tid] = acc;
}

__global__ void k_embed_e(const float* __restrict__ ef, const float* __restrict__ W,
                          const float* __restrict__ b, h16* __restrict__ out) {
    int tid = blockIdx.x * blockDim.x + threadIdx.x;   // NE*64 threads
    int i = tid >> 6, j = tid & 63;
    float r0 = 1.0f / ef[i * 2 + 0];
    float r1 = 1.0f / ef[i * 2 + 1];
    out[tid] = (h16)(b[j] + r0 * W[j] + r1 * W[64 + j]);
}

// ---------------- 64x64 GEMM: Y[r][j] = bias[j] + sum_k X[r][k] W[k][j] ----------------
// wave per 4 rows; W staged in LDS; broadcast X across lanes via __shfl

template <typename TO>
__global__ void k_gemm64(const float* __restrict__ X, const float* __restrict__ W,
                         const float* __restrict__ bias, TO* __restrict__ Y, int nrows) {
    __shared__ float w[64 * 64];
    for (int i = threadIdx.x; i < 4096; i += blockDim.x) w[i] = W[i];
    __syncthreads();
    int lane = threadIdx.x & 63;
    int wave = (blockIdx.x * blockDim.x + threadIdx.x) >> 6;
    int r0 = wave * 4;
    if (r0 >= nrows) return;
    float xv[4], acc[4];
    float bv = bias[lane];
#pragma unroll
    for (int q = 0; q < 4; ++q) { xv[q] = X[(r0 + q) * 64 + lane]; acc[q] = bv; }
#pragma unroll
    for (int k = 0; k < 64; ++k) {
        float cv = w[k * 64 + lane];
#pragma unroll
        for (int q = 0; q < 4; ++q) acc[q] += __shfl(xv[q], k) * cv;
    }
#pragma unroll
    for (int q = 0; q < 4; ++q) Y[(r0 + q) * 64 + lane] = (TO)acc[q];
}

// ---------------- edge pass 1: stats + aggregation atomics (no e_hat store) --------
// e_hat = e@C + Cb + Dh[src] + Eh[dst]; sigma = sigmoid(e_hat)
// atomics: num[dst] += sigma*Bh[src]; den[dst] += sigma; estats += {sum, sumsq}

__global__ void k_edge_stats(const h16* __restrict__ e, const float* __restrict__ CW,
                             const float* __restrict__ Cb, const h16* __restrict__ Bh,
                             const h16* __restrict__ Dh, const h16* __restrict__ Eh,
                             const int* __restrict__ src, const int* __restrict__ dst,
                             float* __restrict__ num, float* __restrict__ den,
                             float* __restrict__ estats) {
    __shared__ float w[64 * 64];
    for (int i = threadIdx.x; i < 4096; i += blockDim.x) w[i] = CW[i];
    __syncthreads();
    int lane = threadIdx.x & 63;
    int wave = (blockIdx.x * blockDim.x + threadIdx.x) >> 6;
    int nwaves = (gridDim.x * blockDim.x) >> 6;
    float cb = Cb[lane];
    float ssum = 0.f, ssq = 0.f;
    for (int g = wave; g < NE / 4; g += nwaves) {
        int e0 = g * 4;
        float ev[4], acc[4];
#pragma unroll
        for (int q = 0; q < 4; ++q) { ev[q] = (float)e[(e0 + q) * 64 + lane]; acc[q] = cb; }
#pragma unroll
        for (int k = 0; k < 64; ++k) {
            float cv = w[k * 64 + lane];
#pragma unroll
            for (int q = 0; q < 4; ++q) acc[q] += __shfl(ev[q], k) * cv;
        }
#pragma unroll
        for (int q = 0; q < 4; ++q) {
            int s = src[e0 + q], d = dst[e0 + q];
            float eh = acc[q] + (float)Dh[s * 64 + lane] + (float)Eh[d * 64 + lane];
            ssum += eh; ssq += eh * eh;
            float sg = 1.0f / (1.0f + __expf(-eh));
            atomicAdd(&num[d * 64 + lane], sg * (float)Bh[s * 64 + lane]);
            atomicAdd(&den[d * 64 + lane], sg);
        }
    }
    atomicAdd(&estats[lane], ssum);
    atomicAdd(&estats[64 + lane], ssq);
}

// ---------------- edge pass 2: recompute e_hat, e += relu(bn(e_hat)) in place ------

__global__ void k_edge_apply(h16* __restrict__ e, const float* __restrict__ CW,
                             const float* __restrict__ Cb, const h16* __restrict__ Dh,
                             const h16* __restrict__ Eh, const int* __restrict__ src,
                             const int* __restrict__ dst, const float* __restrict__ estats,
                             const float* __restrict__ gam, const float* __restrict__ bet) {
    __shared__ float w[64 * 64];
    for (int i = threadIdx.x; i < 4096; i += blockDim.x) w[i] = CW[i];
    __syncthreads();
    int lane = threadIdx.x & 63;
    int wave = (blockIdx.x * blockDim.x + threadIdx.x) >> 6;
    int nwaves = (gridDim.x * blockDim.x) >> 6;
    float cb = Cb[lane];
    float mu = estats[128 + lane], rs = estats[192 + lane];
    float gg = gam[lane], bb = bet[lane];
    for (int g = wave; g < NE / 4; g += nwaves) {
        int e0 = g * 4;
        float ev[4], acc[4];
#pragma unroll
        for (int q = 0; q < 4; ++q) { ev[q] = (float)e[(e0 + q) * 64 + lane]; acc[q] = cb; }
#pragma unroll
        for (int k = 0; k < 64; ++k) {
            float cv = w[k * 64 + lane];
#pragma unroll
            for (int q = 0; q < 4; ++q) acc[q] += __shfl(ev[q], k) * cv;
        }
#pragma unroll
        for (int q = 0; q < 4; ++q) {
            int s = src[e0 + q], d = dst[e0 + q];
            float eh = acc[q] + (float)Dh[s * 64 + lane] + (float)Eh[d * 64 + lane];
            float r = fmaxf(0.f, gg * (eh - mu) * rs + bb);
            e[(e0 + q) * 64 + lane] = (h16)(ev[q] + r);
        }
    }
}

// ---------------- h_new = Ah + num/(den+eps) written into num, with BN stats -------

__global__ void k_hnew(const float* __restrict__ Ah, float* __restrict__ num,
                       const float* __restrict__ den, float* __restrict__ hstats) {
    int lane = threadIdx.x & 63;
    int wave = (blockIdx.x * blockDim.x + threadIdx.x) >> 6;  // NN/4 waves exactly
    float ssum = 0.f, ssq = 0.f;
#pragma unroll
    for (int q = 0; q < 4; ++q) {
        int idx = (wave * 4 + q) * 64 + lane;
        float v = Ah[idx] + num[idx] / (den[idx] + EPS_AGG);
        num[idx] = v; ssum += v; ssq += v * v;
    }
    atomicAdd(&hstats[lane], ssum);
    atomicAdd(&hstats[64 + lane], ssq);
}

// ---------------- finalize BN stats: mu, rsig ----------------

__global__ void k_finstats(float* __restrict__ stats, float count) {
    int j = threadIdx.x;  // 64
    float mu = stats[j] / count;
    float var = stats[64 + j] / count - mu * mu;
    stats[128 + j] = mu;
    stats[192 + j] = 1.0f / sqrtf(var + EPS_BN);
}

// ---------------- h += relu(g*(v-mu)*rsig + beta), float4 ----------------

__global__ void k_bnapply_h(float* __restrict__ xio, const float* __restrict__ val,
                            const float* __restrict__ stats, const float* __restrict__ g,
                            const float* __restrict__ beta, long total4) {
    long t = (long)blockIdx.x * blockDim.x + threadIdx.x;
    long stride = (long)gridDim.x * blockDim.x;
    for (; t < total4; t += stride) {
        int j4 = (int)(t & 15);
        float4 v = ((const float4*)val)[t];
        float4 x = ((const float4*)xio)[t];
        float4 mu = ((const float4*)(stats + 128))[j4];
        float4 rs = ((const float4*)(stats + 192))[j4];
        float4 gg = ((const float4*)g)[j4];
        float4 bb = ((const float4*)beta)[j4];
        x.x += fmaxf(0.f, gg.x * (v.x - mu.x) * rs.x + bb.x);
        x.y += fmaxf(0.f, gg.y * (v.y - mu.y) * rs.y + bb.y);
        x.z += fmaxf(0.f, gg.z * (v.z - mu.z) * rs.z + bb.z);
        x.w += fmaxf(0.f, gg.w * (v.w - mu.w) * rs.w + bb.w);
        ((float4*)xio)[t] = x;
    }
}

// ---------------- readout ----------------

__global__ void k_counts(const int* __restrict__ gid, float* __restrict__ counts) {
    int i = blockIdx.x * blockDim.x + threadIdx.x;
    if (i < NN) atomicAdd(&counts[gid[i]], 1.0f);
}

__global__ void k_hg(const float* __restrict__ h, const int* __restrict__ gid,
                     float* __restrict__ hg) {
    int tid = blockIdx.x * blockDim.x + threadIdx.x;  // NN*64
    int i = tid >> 6, j = tid & 63;
    atomicAdd(&hg[gid[i] * 64 + j], h[tid]);
}

__global__ void k_hgnorm(float* __restrict__ hg, const float* __restrict__ counts) {
    int t = blockIdx.x * blockDim.x + threadIdx.x;  // NB*64
    hg[t] /= fmaxf(counts[t >> 6], 1.0f);
}

// ---------------- MLP ----------------

__global__ void k_mlp1(const float* __restrict__ hg, const float* __restrict__ st,
                       const float* __restrict__ ac, const float* __restrict__ W,
                       const float* __restrict__ b, float* __restrict__ out) {
    __shared__ float x[82];
    int bidx = blockIdx.x, t = threadIdx.x;
    if (t < 64) x[t] = hg[bidx * 64 + t];
    else if (t < 80) x[t] = st[bidx * 16 + (t - 64)];
    else if (t < 82) x[t] = ac[bidx * 2 + (t - 80)];
    __syncthreads();
    float acc = b[t];
#pragma unroll
    for (int k = 0; k < 82; ++k) acc += x[k] * W[k * 256 + t];
    out[bidx * 256 + t] = fmaxf(acc, 0.f);
}

__global__ void k_mlp2(const float* __restrict__ xin, const float* __restrict__ W,
                       const float* __restrict__ b, float* __restrict__ out) {
    __shared__ float x[256];
    int bidx = blockIdx.x, t = threadIdx.x;
    x[t] = xin[bidx * 256 + t];
    __syncthreads();
    float acc = b[t];
#pragma unroll 8
    for (int k = 0; k < 256; ++k) acc += x[k] * W[k * 256 + t];
    out[bidx * 256 + t] = fmaxf(acc, 0.f);
}

__global__ void k_mlp3(const float* __restrict__ xin, const float* __restrict__ W,
                       const float* __restrict__ b, float* __restrict__ out) {
    int t = threadIdx.x;  // NB threads
    float acc = b[0];
#pragma unroll 8
    for (int k = 0; k < 256; ++k) acc += xin[t * 256 + k] * W[k];
    out[t] = acc;
}

// ---------------- launch ----------------

extern "C" void kernel_launch(void* const* d_in, const int* in_sizes, int n_in,
                              void* d_out, int out_size, void* d_ws, size_t ws_size,
                              hipStream_t stream) {
    const float* in_h   = (const float*)d_in[0];
    const float* e_feat = (const float*)d_in[1];
    const int*   src    = (const int*)d_in[2];
    const int*   dst    = (const int*)d_in[3];
    const int*   gid    = (const int*)d_in[4];
    const float* state  = (const float*)d_in[5];
    const float* action = (const float*)d_in[6];
    const float* embhW  = (const float*)d_in[7];
    const float* embhb  = (const float*)d_in[8];
    const float* embeW  = (const float*)d_in[9];
    const float* embeb  = (const float*)d_in[10];
    const float* A_W = (const float*)d_in[11]; const float* A_b = (const float*)d_in[12];
    const float* B_W = (const float*)d_in[13]; const float* B_b = (const float*)d_in[14];
    const float* C_W = (const float*)d_in[15]; const float* C_b = (const float*)d_in[16];
    const float* D_W = (const float*)d_in[17]; const float* D_b = (const float*)d_in[18];
    const float* E_W = (const float*)d_in[19]; const float* E_b = (const float*)d_in[20];
    const float* bnhg = (const float*)d_in[21]; const float* bnhb = (const float*)d_in[22];
    const float* bneg = (const float*)d_in[23]; const float* bneb = (const float*)d_in[24];
    const float* l1W = (const float*)d_in[25]; const float* l1b = (const float*)d_in[26];
    const float* l2W = (const float*)d_in[27]; const float* l2b = (const float*)d_in[28];
    const float* l3W = (const float*)d_in[29]; const float* l3b = (const float*)d_in[30];

    // ---- workspace layout (bytes) ----
    // e (h16)                 : NE*64*2     = 67,108,864
    // h, Ah fp32              : 2 * 8,388,608
    // num, den, hstats, estats: contiguous zero region 2*NN*64 + 512 floats
    // hg, counts              : contiguous zero region NB*64 + NB floats
    // x1, x2                  : 2 * NB*256 floats
    // Bh, Dh, Eh (h16)        : 3 * 4,194,304
    char* base = (char*)d_ws;
    size_t off = 0;
    h16*   e    = (h16*)(base + off);   off += (size_t)NE * 64 * sizeof(h16);
    float* h    = (float*)(base + off); off += (size_t)NN * 64 * sizeof(float);
    float* Ah   = (float*)(base + off); off += (size_t)NN * 64 * sizeof(float);
    float* num  = (float*)(base + off); off += (size_t)NN * 64 * sizeof(float);
    float* den  = (float*)(base + off); off += (size_t)NN * 64 * sizeof(float);
    float* hstats = (float*)(base + off); off += 256 * sizeof(float);
    float* estats = (float*)(base + off); off += 256 * sizeof(float);
    float* hg     = (float*)(base + off); off += (size_t)NB * 64 * sizeof(float);
    float* counts = (float*)(base + off); off += NB * sizeof(float);
    float* x1     = (float*)(base + off); off += (size_t)NB * 256 * sizeof(float);
    float* x2     = (float*)(base + off); off += (size_t)NB * 256 * sizeof(float);
    h16*   Bh   = (h16*)(base + off);   off += (size_t)NN * 64 * sizeof(h16);
    h16*   Dh   = (h16*)(base + off);   off += (size_t)NN * 64 * sizeof(h16);
    h16*   Eh   = (h16*)(base + off);   off += (size_t)NN * 64 * sizeof(h16);

    if (ws_size < off) return;  // diagnostic guard: fail validation, not the GPU

    // embeddings
    k_embed_h<<<(NN * 64) / 256, 256, 0, stream>>>(in_h, embhW, embhb, h);
    k_embed_e<<<(NE * 64) / 256, 256, 0, stream>>>(e_feat, embeW, embeb, e);

    long zero1_n4 = ((long)2 * NN * 64 + 512) / 4;   // num+den+hstats+estats
    for (int l = 0; l < NL; ++l) {
        k_zero4<<<1024, 256, 0, stream>>>((float4*)num, zero1_n4);
        k_gemm64<float><<<NN / 16, 256, 0, stream>>>(h, A_W + l * 4096, A_b + l * 64, Ah, NN);
        k_gemm64<h16><<<NN / 16, 256, 0, stream>>>(h, B_W + l * 4096, B_b + l * 64, Bh, NN);
        k_gemm64<h16><<<NN / 16, 256, 0, stream>>>(h, D_W + l * 4096, D_b + l * 64, Dh, NN);
        k_gemm64<h16><<<NN / 16, 256, 0, stream>>>(h, E_W + l * 4096, E_b + l * 64, Eh, NN);
        k_edge_stats<<<2048, 256, 0, stream>>>(e, C_W + l * 4096, C_b + l * 64, Bh, Dh, Eh,
                                               src, dst, num, den, estats);
        k_finstats<<<1, 64, 0, stream>>>(estats, (float)NE);
        k_edge_apply<<<2048, 256, 0, stream>>>(e, C_W + l * 4096, C_b + l * 64, Dh, Eh,
                                               src, dst, estats, bneg + l * 64, bneb + l * 64);
        k_hnew<<<NN / 16, 256, 0, stream>>>(Ah, num, den, hstats);
        k_finstats<<<1, 64, 0, stream>>>(hstats, (float)NN);
        k_bnapply_h<<<2048, 256, 0, stream>>>(h, num, hstats, bnhg + l * 64, bnhb + l * 64,
                                              (long)NN * 16);
    }

    // readout
    k_zero4<<<64, 256, 0, stream>>>((float4*)hg, (long)(NB * 64 + NB) / 4);
    k_counts<<<NN / 256, 256, 0, stream>>>(gid, counts);
    k_hg<<<(NN * 64) / 256, 256, 0, stream>>>(h, gid, hg);
    k_hgnorm<<<(NB * 64) / 256, 256, 0, stream>>>(hg, counts);

    // MLP
    k_mlp1<<<NB, 256, 0, stream>>>(hg, state, action, l1W, l1b, x1);
    k_mlp2<<<NB, 256, 0, stream>>>(x1, l2W, l2b, x2);
    k_mlp3<<<1, NB, 0, stream>>>(x2, l3W, l3b, (float*)d_out);
}